// Round 4
// baseline (289.984 us; speedup 1.0000x reference)
//
#include <hip/hip_runtime.h>
#include <math.h>
#include <stdint.h>

#define NB 16
#define SQ 1024
#define DD 1024

typedef _Float16 f16x8 __attribute__((ext_vector_type(8)));
typedef _Float16 f16x4 __attribute__((ext_vector_type(4)));
typedef float f32x4 __attribute__((ext_vector_type(4)));

// ---------------- prep: special-token masks, lengths, temperatures ----------------
__global__ void prep_kernel(const int* __restrict__ ids_src, const int* __restrict__ ids_tgt,
                            float* __restrict__ add_src, float* __restrict__ add_tgt,
                            float* __restrict__ itau){
  int b = blockIdx.x;
  __shared__ int csrc, ctgt;
  if (threadIdx.x == 0){ csrc = 0; ctgt = 0; }
  __syncthreads();
  int ls = 0, lt = 0;
  for (int i = threadIdx.x; i < SQ; i += blockDim.x){
    int id = ids_src[b*SQ + i];
    bool sp = (id == 0) || (id == 101) || (id == 102);
    add_src[b*SQ + i] = sp ? -10000.0f : 0.0f;
    ls += sp ? 0 : 1;
    id = ids_tgt[b*SQ + i];
    sp = (id == 0) || (id == 101) || (id == 102);
    add_tgt[b*SQ + i] = sp ? -10000.0f : 0.0f;
    lt += sp ? 0 : 1;
  }
  atomicAdd(&csrc, ls);
  atomicAdd(&ctgt, lt);
  __syncthreads();
  if (threadIdx.x == 0){
    itau[b]      = 1.0f / sqrtf((float)csrc);   // 1/sqrt(len_src)
    itau[NB + b] = 1.0f / sqrtf((float)ctgt);   // 1/sqrt(len_tgt)
  }
}

// ---------------- split conversion: fp32 -> hi fp16 + lo fp16 (x - hi scaled by 2^12) ----------------
__global__ __launch_bounds__(256)
void convert_split(const float* __restrict__ X, _Float16* __restrict__ Hi, _Float16* __restrict__ Lo){
  size_t i = ((size_t)blockIdx.x*256 + threadIdx.x)*4;
  float4 v = *(const float4*)(X + i);
  float xs[4] = {v.x, v.y, v.z, v.w};
  f16x4 h, l;
  #pragma unroll
  for (int j = 0; j < 4; ++j){
    _Float16 hh = (_Float16)xs[j];
    h[j] = hh;
    l[j] = (_Float16)((xs[j] - (float)hh) * 4096.0f);
  }
  *(f16x4*)(Hi + i) = h;
  *(f16x4*)(Lo + i) = l;
}

// ---------------- split-fp16 MFMA GEMM: scores[b] = hsrc[b] @ htgt[b]^T ----------------
// 128x128 tile, BK=32, 4 waves (2x2 of 64x64), mfma_f32_16x16x32_f16, double-buffered LDS,
// global_load_lds w16 with source-side XOR swizzle (slot ^= row&3), XCD block swizzle.
typedef const uint32_t __attribute__((address_space(1))) gu32_t;
typedef uint32_t __attribute__((address_space(3))) su32_t;

__device__ __forceinline__ void gload16(const void* g, void* l){
  __builtin_amdgcn_global_load_lds((gu32_t*)g, (su32_t*)l, 16, 0, 0);
}

#define NKS 32   // 1024/32

__global__ __launch_bounds__(256, 2)
void gemm_split(const _Float16* __restrict__ Ahi, const _Float16* __restrict__ Alo,
                const _Float16* __restrict__ Bhi, const _Float16* __restrict__ Blo,
                float* __restrict__ C){
  __shared__ _Float16 lds[2][4][128*32];   // [buf][plane: Ahi,Alo,Bhi,Blo][row*32 + swizzled k]
  const int tid  = threadIdx.x;
  const int wave = tid >> 6;
  const int lane = tid & 63;

  // XCD-aware swizzle (1024 blocks, 1024 % 8 == 0 -> bijective)
  int bid = blockIdx.x;
  int wg  = (bid & 7) * (1024/8) + (bid >> 3);
  int b   = wg >> 6;
  int by  = (wg >> 3) & 7;
  int bx  = wg & 7;

  const size_t abase = ((size_t)b*SQ + by*128) * DD;
  const size_t bbase = ((size_t)b*SQ + bx*128) * DD;
  const _Float16* srcs[4] = {Ahi + abase, Alo + abase, Bhi + bbase, Blo + bbase};

  // staging geometry: thread i covers LDS 16B slot i (linear); global source pre-swizzled
  const uint32_t rr = tid >> 2;                 // row within 64-row issue
  const uint32_t sl = (tid & 3) ^ (rr & 3);     // swizzled k-slot (8 fp16 each)
  const size_t  goff = (size_t)rr*DD + sl*8;

  // fragment read offsets (fp16 elems): row*32 + swizzled_slot*8; row&3 == lane&3
  const int ls8 = (((lane >> 4) ^ (lane & 3)) << 3);
  const int wm  = (wave >> 1) * 64;
  const int wn  = (wave & 1) * 64;
  const int lr  = lane & 15;
  const int aoffL = (wm + lr)*32 + ls8;
  const int boffL = (wn + lr)*32 + ls8;

  f32x4 accm[4][4], accc[4][4];
  #pragma unroll
  for (int m = 0; m < 4; ++m)
    #pragma unroll
    for (int n = 0; n < 4; ++n){ accm[m][n] = (f32x4)0.0f; accc[m][n] = (f32x4)0.0f; }

  // prologue stage into buf 0
  {
    #pragma unroll
    for (int p = 0; p < 4; ++p){
      const _Float16* g = srcs[p] + goff;
      _Float16* l0 = &lds[0][p][0] + wave*512;
      gload16(g, l0);
      gload16(g + 64*DD, l0 + 2048);
    }
  }
  __syncthreads();

  int buf = 0;
  for (int t = 0; t < NKS; ++t){
    if (t + 1 < NKS){
      const int k0 = (t + 1) * 32;
      #pragma unroll
      for (int p = 0; p < 4; ++p){
        const _Float16* g = srcs[p] + k0 + goff;
        _Float16* l0 = &lds[buf^1][p][0] + wave*512;
        gload16(g, l0);
        gload16(g + 64*DD, l0 + 2048);
      }
    }

    f16x8 ah[4], al[4], bh[4], bl[4];
    #pragma unroll
    for (int m = 0; m < 4; ++m){
      ah[m] = *(const f16x8*)&lds[buf][0][aoffL + m*512];
      al[m] = *(const f16x8*)&lds[buf][1][aoffL + m*512];
      bh[m] = *(const f16x8*)&lds[buf][2][boffL + m*512];
      bl[m] = *(const f16x8*)&lds[buf][3][boffL + m*512];
    }
    #pragma unroll
    for (int m = 0; m < 4; ++m)
      #pragma unroll
      for (int n = 0; n < 4; ++n){
        accm[m][n] = __builtin_amdgcn_mfma_f32_16x16x32_f16(ah[m], bh[n], accm[m][n], 0, 0, 0);
        accc[m][n] = __builtin_amdgcn_mfma_f32_16x16x32_f16(ah[m], bl[n], accc[m][n], 0, 0, 0);
        accc[m][n] = __builtin_amdgcn_mfma_f32_16x16x32_f16(al[m], bh[n], accc[m][n], 0, 0, 0);
      }
    __syncthreads();
    buf ^= 1;
  }

  // epilogue: C/D layout col=lane&15, row=(lane>>4)*4+reg
  float* Cb = C + ((size_t)b*SQ + by*128 + wm)*SQ + bx*128 + wn;
  const float inv = 1.0f / 4096.0f;
  const int r0 = (lane >> 4) * 4;
  const int c0 = lane & 15;
  #pragma unroll
  for (int m = 0; m < 4; ++m)
    #pragma unroll
    for (int n = 0; n < 4; ++n){
      #pragma unroll
      for (int j = 0; j < 4; ++j){
        float r = accm[m][n][j] + accc[m][n][j]*inv;
        Cb[(size_t)(m*16 + r0 + j)*SQ + n*16 + c0] = r;
      }
    }
}

// ---------------- fp32 fallback GEMM (round-1) ----------------
__global__ __launch_bounds__(256)
void gemm_nt(const float* __restrict__ A, const float* __restrict__ Bm, float* __restrict__ C){
  __shared__ float As[32][132];
  __shared__ float Bs[32][132];
  const int b = blockIdx.z;
  const float* Ab = A  + ((size_t)b*SQ + blockIdx.y*128) * DD;
  const float* Bb = Bm + ((size_t)b*SQ + blockIdx.x*128) * DD;
  const int tid = threadIdx.x;
  const int lr = tid >> 3;
  const int lc = (tid & 7) << 2;
  const int tx = tid & 15;
  const int ty = tid >> 4;

  float acc[8][8];
  #pragma unroll
  for (int i = 0; i < 8; ++i)
    #pragma unroll
    for (int j = 0; j < 8; ++j) acc[i][j] = 0.0f;

  for (int k0 = 0; k0 < DD; k0 += 32){
    #pragma unroll
    for (int p = 0; p < 4; ++p){
      int row = p*32 + lr;
      float4 va = *(const float4*)(Ab + (size_t)row*DD + k0 + lc);
      float4 vb = *(const float4*)(Bb + (size_t)row*DD + k0 + lc);
      As[lc+0][row] = va.x; As[lc+1][row] = va.y; As[lc+2][row] = va.z; As[lc+3][row] = va.w;
      Bs[lc+0][row] = vb.x; Bs[lc+1][row] = vb.y; Bs[lc+2][row] = vb.z; Bs[lc+3][row] = vb.w;
    }
    __syncthreads();
    #pragma unroll
    for (int k = 0; k < 32; ++k){
      float a[8], bb[8];
      *(float4*)(a)    = *(const float4*)&As[k][ty*4];
      *(float4*)(a+4)  = *(const float4*)&As[k][64 + ty*4];
      *(float4*)(bb)   = *(const float4*)&Bs[k][tx*4];
      *(float4*)(bb+4) = *(const float4*)&Bs[k][64 + tx*4];
      #pragma unroll
      for (int i = 0; i < 8; ++i)
        #pragma unroll
        for (int j = 0; j < 8; ++j)
          acc[i][j] = fmaf(a[i], bb[j], acc[i][j]);
    }
    __syncthreads();
  }

  float* Cb = C + (size_t)b*SQ*SQ + (size_t)(blockIdx.y*128)*SQ + blockIdx.x*128;
  #pragma unroll
  for (int i = 0; i < 8; ++i){
    int r = (i < 4) ? (ty*4 + i) : (64 + ty*4 + (i-4));
    *(float4*)(Cb + (size_t)r*SQ + tx*4)      = make_float4(acc[i][0],acc[i][1],acc[i][2],acc[i][3]);
    *(float4*)(Cb + (size_t)r*SQ + 64 + tx*4) = make_float4(acc[i][4],acc[i][5],acc[i][6],acc[i][7]);
  }
}

// ---------------- row stats ----------------
__global__ __launch_bounds__(256)
void row_stats(const float* __restrict__ scores, const float* __restrict__ add_tgt,
               const float* __restrict__ itau,
               float* __restrict__ Mr, float* __restrict__ S1r, float* __restrict__ S2r){
  int wv = threadIdx.x >> 6, lane = threadIdx.x & 63;
  int row = blockIdx.x*4 + wv;
  int b = row >> 10;
  float it = itau[NB + b];
  const float* p  = scores  + (size_t)row*SQ;
  const float* at = add_tgt + b*SQ;
  float x[16];
  #pragma unroll
  for (int c = 0; c < 4; ++c){
    float4 v = *(const float4*)(p  + c*256 + lane*4);
    float4 a = *(const float4*)(at + c*256 + lane*4);
    x[c*4+0] = v.x + a.x; x[c*4+1] = v.y + a.y;
    x[c*4+2] = v.z + a.z; x[c*4+3] = v.w + a.w;
  }
  float mx = x[0];
  #pragma unroll
  for (int i = 1; i < 16; ++i) mx = fmaxf(mx, x[i]);
  #pragma unroll
  for (int o = 32; o > 0; o >>= 1) mx = fmaxf(mx, __shfl_xor(mx, o));
  float s1 = 0.f, s2 = 0.f;
  #pragma unroll
  for (int i = 0; i < 16; ++i){
    float d = x[i] - mx;
    s1 += expf(d);
    s2 += expf(d * it);
  }
  #pragma unroll
  for (int o = 32; o > 0; o >>= 1){ s1 += __shfl_xor(s1, o); s2 += __shfl_xor(s2, o); }
  if (lane == 0){ Mr[row] = mx; S1r[row] = s1; S2r[row] = s2; }
}

// ---------------- column stats ----------------
#define NCH 64
#define CHROWS 16
__global__ __launch_bounds__(256)
void col_part(const float* __restrict__ scores, const float* __restrict__ add_src,
              const float* __restrict__ itau, float* __restrict__ part){
  int b = blockIdx.x / NCH, ch = blockIdx.x % NCH;
  int t = threadIdx.x << 2;
  float it = itau[b];
  const float* p  = scores  + ((size_t)b*SQ + ch*CHROWS)*SQ + t;
  const float* as = add_src + b*SQ + ch*CHROWS;
  float m[4], s1[4], s2[4];
  #pragma unroll
  for (int j = 0; j < 4; ++j){ m[j] = -1e30f; s1[j] = 0.f; s2[j] = 0.f; }
  for (int s = 0; s < CHROWS; ++s){
    float ad = as[s];
    float4 v = *(const float4*)(p + (size_t)s*SQ);
    float xv[4] = {v.x+ad, v.y+ad, v.z+ad, v.w+ad};
    #pragma unroll
    for (int j = 0; j < 4; ++j){
      float mn = fmaxf(m[j], xv[j]);
      s1[j] = s1[j]*expf(m[j]-mn)      + expf(xv[j]-mn);
      s2[j] = s2[j]*expf((m[j]-mn)*it) + expf((xv[j]-mn)*it);
      m[j] = mn;
    }
  }
  size_t base = (size_t)blockIdx.x * 3 * SQ + t;
  *(float4*)(part + base)        = make_float4(m[0],m[1],m[2],m[3]);
  *(float4*)(part + base + SQ)   = make_float4(s1[0],s1[1],s1[2],s1[3]);
  *(float4*)(part + base + 2*SQ) = make_float4(s2[0],s2[1],s2[2],s2[3]);
}

__global__ void col_merge(const float* __restrict__ part, const float* __restrict__ itau,
                          float* __restrict__ Mc, float* __restrict__ S1c, float* __restrict__ S2c){
  int idx = blockIdx.x*256 + threadIdx.x;
  int b = idx >> 10;
  int t = idx & 1023;
  float it = itau[b];
  float M = -1e30f;
  for (int ch = 0; ch < NCH; ++ch)
    M = fmaxf(M, part[(size_t)(b*NCH+ch)*3*SQ + t]);
  float s1 = 0.f, s2 = 0.f;
  for (int ch = 0; ch < NCH; ++ch){
    size_t base = (size_t)(b*NCH+ch)*3*SQ + t;
    float mm = part[base];
    s1 += part[base +   SQ] * expf(mm - M);
    s2 += part[base + 2*SQ] * expf((mm - M)*it);
  }
  Mc[idx] = M; S1c[idx] = s1; S2c[idx] = s2;
}

// ---------------- finalize ----------------
__global__ __launch_bounds__(256)
void finalize(const float* __restrict__ scores,
              const float* __restrict__ add_src, const float* __restrict__ add_tgt,
              const float* __restrict__ itau,
              const float* __restrict__ Mr, const float* __restrict__ S1r, const float* __restrict__ S2r,
              const float* __restrict__ Mc, const float* __restrict__ S1c, const float* __restrict__ S2c,
              float* __restrict__ out0, float* __restrict__ out1){
  int row = blockIdx.x;
  int b = row >> 10;
  float Mrv = Mr[row], s1r = S1r[row], s2r = S2r[row];
  float ads = add_src[row];
  float itt = itau[NB + b], its = itau[b];
  int t = threadIdx.x << 2;
  size_t off = (size_t)row*SQ + t;
  float4 x4  = *(const float4*)(scores + off);
  int bt = b*SQ + t;
  float4 at4 = *(const float4*)(add_tgt + bt);
  float4 mc4 = *(const float4*)(Mc  + bt);
  float4 c14 = *(const float4*)(S1c + bt);
  float4 c24 = *(const float4*)(S2c + bt);
  const float* xp  = (const float*)&x4;
  const float* atp = (const float*)&at4;
  const float* mcp = (const float*)&mc4;
  const float* c1p = (const float*)&c14;
  const float* c2p = (const float*)&c24;
  float o0[4], o1[4];
  #pragma unroll
  for (int j = 0; j < 4; ++j){
    float x  = xp[j];
    float xs = x + atp[j];
    float ps = expf(xs - Mrv) / s1r;
    float qs = expf((xs - Mrv)*itt) / s2r;
    float xt = x + ads;
    float pt = expf(xt - mcp[j]) / c1p[j];
    float qt = expf((xt - mcp[j])*its) / c2p[j];
    o0[j] = (ps > 1e-3f && pt > 1e-3f) ? 1.0f : 0.0f;
    o1[j] = 2.0f*qs*qt / (qs + qt + 1e-9f);
  }
  *(float4*)(out0 + off) = make_float4(o0[0],o0[1],o0[2],o0[3]);
  *(float4*)(out1 + off) = make_float4(o1[0],o1[1],o1[2],o1[3]);
}

extern "C" void kernel_launch(void* const* d_in, const int* in_sizes, int n_in,
                              void* d_out, int out_size, void* d_ws, size_t ws_size,
                              hipStream_t stream){
  const float* hsrc = (const float*)d_in[0];
  const float* htgt = (const float*)d_in[1];
  const int*   isrc = (const int*)d_in[2];
  const int*   itgt = (const int*)d_in[3];

  float* out0 = (float*)d_out;
  float* out1 = out0 + (size_t)NB*SQ*SQ;
  float* W = (float*)d_ws;

  const size_t NSQ2 = (size_t)NB*SQ*SQ;              // 16,777,216
  // fast-path ws layout (floats)
  const size_t need_fast = (NSQ2 + 16384*2 + 32 + 6*NB*SQ + (size_t)NB*NCH*3*SQ) * 4;

  if (ws_size >= need_fast){
    float* scores  = W;                         // 16M floats
    float* add_src = W + NSQ2;
    float* add_tgt = add_src + NB*SQ;
    float* itau    = add_tgt + NB*SQ;
    float* Mr      = itau + 32;
    float* S1r     = Mr  + NB*SQ;
    float* S2r     = S1r + NB*SQ;
    float* Mc      = S2r + NB*SQ;
    float* S1c     = Mc  + NB*SQ;
    float* S2c     = S1c + NB*SQ;
    float* part    = S2c + NB*SQ;

    _Float16* Ahi = (_Float16*)out0;            // planes live in d_out halves until finalize
    _Float16* Alo = Ahi + NSQ2;
    _Float16* Bhi = (_Float16*)out1;
    _Float16* Blo = Bhi + NSQ2;

    prep_kernel<<<NB, 256, 0, stream>>>(isrc, itgt, add_src, add_tgt, itau);
    convert_split<<<NSQ2/1024, 256, 0, stream>>>(hsrc, Ahi, Alo);
    convert_split<<<NSQ2/1024, 256, 0, stream>>>(htgt, Bhi, Blo);
    gemm_split<<<1024, 256, 0, stream>>>(Ahi, Alo, Bhi, Blo, scores);
    row_stats<<<NB*SQ/4, 256, 0, stream>>>(scores, add_tgt, itau, Mr, S1r, S2r);
    col_part<<<NB*NCH, 256, 0, stream>>>(scores, add_src, itau, part);
    col_merge<<<NB*SQ/256, 256, 0, stream>>>(part, itau, Mc, S1c, S2c);
    finalize<<<NB*SQ, 256, 0, stream>>>(scores, add_src, add_tgt, itau,
                                        Mr, S1r, S2r, Mc, S1c, S2c, out0, out1);
  } else {
    // fallback: round-1 fp32 path, scores staged in out1
    float* scores  = out1;
    float* add_src = W;
    float* add_tgt = W + 16384;
    float* itau    = W + 32768;
    float* Mr      = W + 32800;
    float* S1r     = Mr  + NB*SQ;
    float* S2r     = S1r + NB*SQ;
    float* Mc      = S2r + NB*SQ;
    float* S1c     = Mc  + NB*SQ;
    float* S2c     = S1c + NB*SQ;
    float* part    = S2c + NB*SQ;

    prep_kernel<<<NB, 256, 0, stream>>>(isrc, itgt, add_src, add_tgt, itau);
    gemm_nt<<<dim3(8, 8, NB), 256, 0, stream>>>(hsrc, htgt, scores);
    row_stats<<<NB*SQ/4, 256, 0, stream>>>(scores, add_tgt, itau, Mr, S1r, S2r);
    col_part<<<NB*NCH, 256, 0, stream>>>(scores, add_src, itau, part);
    col_merge<<<NB*SQ/256, 256, 0, stream>>>(part, itau, Mc, S1c, S2c);
    finalize<<<NB*SQ, 256, 0, stream>>>(scores, add_src, add_tgt, itau,
                                        Mr, S1r, S2r, Mc, S1c, S2c, out0, out1);
  }
}

// Round 5
// 287.342 us; speedup vs baseline: 1.0092x; 1.0092x over previous
//
#include <hip/hip_runtime.h>
#include <math.h>
#include <stdint.h>

#define NB 16
#define SQ 1024
#define DD 1024

typedef _Float16 f16x8 __attribute__((ext_vector_type(8)));
typedef _Float16 f16x4 __attribute__((ext_vector_type(4)));
typedef float f32x4 __attribute__((ext_vector_type(4)));

// ---------------- prep: special-token masks, lengths, temperatures ----------------
__global__ void prep_kernel(const int* __restrict__ ids_src, const int* __restrict__ ids_tgt,
                            float* __restrict__ add_src, float* __restrict__ add_tgt,
                            float* __restrict__ itau){
  int b = blockIdx.x;
  __shared__ int csrc, ctgt;
  if (threadIdx.x == 0){ csrc = 0; ctgt = 0; }
  __syncthreads();
  int ls = 0, lt = 0;
  for (int i = threadIdx.x; i < SQ; i += blockDim.x){
    int id = ids_src[b*SQ + i];
    bool sp = (id == 0) || (id == 101) || (id == 102);
    add_src[b*SQ + i] = sp ? -10000.0f : 0.0f;
    ls += sp ? 0 : 1;
    id = ids_tgt[b*SQ + i];
    sp = (id == 0) || (id == 101) || (id == 102);
    add_tgt[b*SQ + i] = sp ? -10000.0f : 0.0f;
    lt += sp ? 0 : 1;
  }
  atomicAdd(&csrc, ls);
  atomicAdd(&ctgt, lt);
  __syncthreads();
  if (threadIdx.x == 0){
    itau[b]      = 1.0f / sqrtf((float)csrc);   // 1/sqrt(len_src)
    itau[NB + b] = 1.0f / sqrtf((float)ctgt);   // 1/sqrt(len_tgt)
  }
}

// ---------------- split conversion: fp32 -> hi fp16 + lo fp16 (x - hi scaled by 2^12) ----------------
__global__ __launch_bounds__(256)
void convert_split(const float* __restrict__ X, _Float16* __restrict__ Hi, _Float16* __restrict__ Lo){
  size_t i = ((size_t)blockIdx.x*256 + threadIdx.x)*4;
  float4 v = *(const float4*)(X + i);
  float xs[4] = {v.x, v.y, v.z, v.w};
  f16x4 h, l;
  #pragma unroll
  for (int j = 0; j < 4; ++j){
    _Float16 hh = (_Float16)xs[j];
    h[j] = hh;
    l[j] = (_Float16)((xs[j] - (float)hh) * 4096.0f);
  }
  *(f16x4*)(Hi + i) = h;
  *(f16x4*)(Lo + i) = l;
}

// ---------------- split-fp16 MFMA GEMM: scores[b] = hsrc[b] @ htgt[b]^T ----------------
// 128x128 tile, BK=32, 4 waves (2x2 of 64x64), mfma_f32_16x16x32_f16, double-buffered LDS,
// global_load_lds w16 with source-side XOR swizzle (slot ^= row&3), XCD block swizzle.
typedef const uint32_t __attribute__((address_space(1))) gu32_t;
typedef uint32_t __attribute__((address_space(3))) su32_t;

__device__ __forceinline__ void gload16(const void* g, void* l){
  __builtin_amdgcn_global_load_lds((gu32_t*)g, (su32_t*)l, 16, 0, 0);
}

#define NKS 32   // 1024/32

__global__ __launch_bounds__(256, 2)
void gemm_split(const _Float16* __restrict__ Ahi, const _Float16* __restrict__ Alo,
                const _Float16* __restrict__ Bhi, const _Float16* __restrict__ Blo,
                float* __restrict__ C){
  __shared__ _Float16 lds[2][4][128*32];   // [buf][plane: Ahi,Alo,Bhi,Blo][row*32 + swizzled k]
  const int tid  = threadIdx.x;
  const int wave = tid >> 6;
  const int lane = tid & 63;

  // XCD-aware swizzle (1024 blocks, 1024 % 8 == 0 -> bijective)
  int bid = blockIdx.x;
  int wg  = (bid & 7) * (1024/8) + (bid >> 3);
  int b   = wg >> 6;
  int by  = (wg >> 3) & 7;
  int bx  = wg & 7;

  const size_t abase = ((size_t)b*SQ + by*128) * DD;
  const size_t bbase = ((size_t)b*SQ + bx*128) * DD;
  const _Float16* srcs[4] = {Ahi + abase, Alo + abase, Bhi + bbase, Blo + bbase};

  // staging geometry: thread i covers LDS 16B slot i (linear); global source pre-swizzled
  const uint32_t rr = tid >> 2;                 // row within 64-row issue
  const uint32_t sl = (tid & 3) ^ (rr & 3);     // swizzled k-slot (8 fp16 each)
  const size_t  goff = (size_t)rr*DD + sl*8;

  // fragment read offsets (fp16 elems): row*32 + swizzled_slot*8; row&3 == lane&3
  const int ls8 = (((lane >> 4) ^ (lane & 3)) << 3);
  const int wm  = (wave >> 1) * 64;
  const int wn  = (wave & 1) * 64;
  const int lr  = lane & 15;
  const int aoffL = (wm + lr)*32 + ls8;
  const int boffL = (wn + lr)*32 + ls8;

  f32x4 accm[4][4], accc[4][4];
  #pragma unroll
  for (int m = 0; m < 4; ++m)
    #pragma unroll
    for (int n = 0; n < 4; ++n){ accm[m][n] = (f32x4)0.0f; accc[m][n] = (f32x4)0.0f; }

  // prologue stage into buf 0
  {
    #pragma unroll
    for (int p = 0; p < 4; ++p){
      const _Float16* g = srcs[p] + goff;
      _Float16* l0 = &lds[0][p][0] + wave*512;
      gload16(g, l0);
      gload16(g + 64*DD, l0 + 2048);
    }
  }
  __syncthreads();

  int buf = 0;
  for (int t = 0; t < NKS; ++t){
    if (t + 1 < NKS){
      const int k0 = (t + 1) * 32;
      #pragma unroll
      for (int p = 0; p < 4; ++p){
        const _Float16* g = srcs[p] + k0 + goff;
        _Float16* l0 = &lds[buf^1][p][0] + wave*512;
        gload16(g, l0);
        gload16(g + 64*DD, l0 + 2048);
      }
    }

    f16x8 ah[4], al[4], bh[4], bl[4];
    #pragma unroll
    for (int m = 0; m < 4; ++m){
      ah[m] = *(const f16x8*)&lds[buf][0][aoffL + m*512];
      al[m] = *(const f16x8*)&lds[buf][1][aoffL + m*512];
      bh[m] = *(const f16x8*)&lds[buf][2][boffL + m*512];
      bl[m] = *(const f16x8*)&lds[buf][3][boffL + m*512];
    }
    #pragma unroll
    for (int m = 0; m < 4; ++m)
      #pragma unroll
      for (int n = 0; n < 4; ++n){
        accm[m][n] = __builtin_amdgcn_mfma_f32_16x16x32_f16(ah[m], bh[n], accm[m][n], 0, 0, 0);
        accc[m][n] = __builtin_amdgcn_mfma_f32_16x16x32_f16(ah[m], bl[n], accc[m][n], 0, 0, 0);
        accc[m][n] = __builtin_amdgcn_mfma_f32_16x16x32_f16(al[m], bh[n], accc[m][n], 0, 0, 0);
      }
    __syncthreads();
    buf ^= 1;
  }

  // epilogue: C/D layout col=lane&15, row=(lane>>4)*4+reg
  float* Cb = C + ((size_t)b*SQ + by*128 + wm)*SQ + bx*128 + wn;
  const float inv = 1.0f / 4096.0f;
  const int r0 = (lane >> 4) * 4;
  const int c0 = lane & 15;
  #pragma unroll
  for (int m = 0; m < 4; ++m)
    #pragma unroll
    for (int n = 0; n < 4; ++n){
      #pragma unroll
      for (int j = 0; j < 4; ++j){
        float r = accm[m][n][j] + accc[m][n][j]*inv;
        Cb[(size_t)(m*16 + r0 + j)*SQ + n*16 + c0] = r;
      }
    }
}

// ---------------- fp32 fallback GEMM (round-1) ----------------
__global__ __launch_bounds__(256)
void gemm_nt(const float* __restrict__ A, const float* __restrict__ Bm, float* __restrict__ C){
  __shared__ float As[32][132];
  __shared__ float Bs[32][132];
  const int b = blockIdx.z;
  const float* Ab = A  + ((size_t)b*SQ + blockIdx.y*128) * DD;
  const float* Bb = Bm + ((size_t)b*SQ + blockIdx.x*128) * DD;
  const int tid = threadIdx.x;
  const int lr = tid >> 3;
  const int lc = (tid & 7) << 2;
  const int tx = tid & 15;
  const int ty = tid >> 4;

  float acc[8][8];
  #pragma unroll
  for (int i = 0; i < 8; ++i)
    #pragma unroll
    for (int j = 0; j < 8; ++j) acc[i][j] = 0.0f;

  for (int k0 = 0; k0 < DD; k0 += 32){
    #pragma unroll
    for (int p = 0; p < 4; ++p){
      int row = p*32 + lr;
      float4 va = *(const float4*)(Ab + (size_t)row*DD + k0 + lc);
      float4 vb = *(const float4*)(Bb + (size_t)row*DD + k0 + lc);
      As[lc+0][row] = va.x; As[lc+1][row] = va.y; As[lc+2][row] = va.z; As[lc+3][row] = va.w;
      Bs[lc+0][row] = vb.x; Bs[lc+1][row] = vb.y; Bs[lc+2][row] = vb.z; Bs[lc+3][row] = vb.w;
    }
    __syncthreads();
    #pragma unroll
    for (int k = 0; k < 32; ++k){
      float a[8], bb[8];
      *(float4*)(a)    = *(const float4*)&As[k][ty*4];
      *(float4*)(a+4)  = *(const float4*)&As[k][64 + ty*4];
      *(float4*)(bb)   = *(const float4*)&Bs[k][tx*4];
      *(float4*)(bb+4) = *(const float4*)&Bs[k][64 + tx*4];
      #pragma unroll
      for (int i = 0; i < 8; ++i)
        #pragma unroll
        for (int j = 0; j < 8; ++j)
          acc[i][j] = fmaf(a[i], bb[j], acc[i][j]);
    }
    __syncthreads();
  }

  float* Cb = C + (size_t)b*SQ*SQ + (size_t)(blockIdx.y*128)*SQ + blockIdx.x*128;
  #pragma unroll
  for (int i = 0; i < 8; ++i){
    int r = (i < 4) ? (ty*4 + i) : (64 + ty*4 + (i-4));
    *(float4*)(Cb + (size_t)r*SQ + tx*4)      = make_float4(acc[i][0],acc[i][1],acc[i][2],acc[i][3]);
    *(float4*)(Cb + (size_t)r*SQ + 64 + tx*4) = make_float4(acc[i][4],acc[i][5],acc[i][6],acc[i][7]);
  }
}

// ---------------- row stats ----------------
__global__ __launch_bounds__(256)
void row_stats(const float* __restrict__ scores, const float* __restrict__ add_tgt,
               const float* __restrict__ itau,
               float* __restrict__ Mr, float* __restrict__ S1r, float* __restrict__ S2r){
  int wv = threadIdx.x >> 6, lane = threadIdx.x & 63;
  int row = blockIdx.x*4 + wv;
  int b = row >> 10;
  float it = itau[NB + b];
  const float* p  = scores  + (size_t)row*SQ;
  const float* at = add_tgt + b*SQ;
  float x[16];
  #pragma unroll
  for (int c = 0; c < 4; ++c){
    float4 v = *(const float4*)(p  + c*256 + lane*4);
    float4 a = *(const float4*)(at + c*256 + lane*4);
    x[c*4+0] = v.x + a.x; x[c*4+1] = v.y + a.y;
    x[c*4+2] = v.z + a.z; x[c*4+3] = v.w + a.w;
  }
  float mx = x[0];
  #pragma unroll
  for (int i = 1; i < 16; ++i) mx = fmaxf(mx, x[i]);
  #pragma unroll
  for (int o = 32; o > 0; o >>= 1) mx = fmaxf(mx, __shfl_xor(mx, o));
  float s1 = 0.f, s2 = 0.f;
  #pragma unroll
  for (int i = 0; i < 16; ++i){
    float d = x[i] - mx;
    s1 += expf(d);
    s2 += expf(d * it);
  }
  #pragma unroll
  for (int o = 32; o > 0; o >>= 1){ s1 += __shfl_xor(s1, o); s2 += __shfl_xor(s2, o); }
  if (lane == 0){ Mr[row] = mx; S1r[row] = s1; S2r[row] = s2; }
}

// ---------------- column stats ----------------
#define NCH 64
#define CHROWS 16
__global__ __launch_bounds__(256)
void col_part(const float* __restrict__ scores, const float* __restrict__ add_src,
              const float* __restrict__ itau, float* __restrict__ part){
  int b = blockIdx.x / NCH, ch = blockIdx.x % NCH;
  int t = threadIdx.x << 2;
  float it = itau[b];
  const float* p  = scores  + ((size_t)b*SQ + ch*CHROWS)*SQ + t;
  const float* as = add_src + b*SQ + ch*CHROWS;
  float m[4], s1[4], s2[4];
  #pragma unroll
  for (int j = 0; j < 4; ++j){ m[j] = -1e30f; s1[j] = 0.f; s2[j] = 0.f; }
  for (int s = 0; s < CHROWS; ++s){
    float ad = as[s];
    float4 v = *(const float4*)(p + (size_t)s*SQ);
    float xv[4] = {v.x+ad, v.y+ad, v.z+ad, v.w+ad};
    #pragma unroll
    for (int j = 0; j < 4; ++j){
      float mn = fmaxf(m[j], xv[j]);
      s1[j] = s1[j]*expf(m[j]-mn)      + expf(xv[j]-mn);
      s2[j] = s2[j]*expf((m[j]-mn)*it) + expf((xv[j]-mn)*it);
      m[j] = mn;
    }
  }
  size_t base = (size_t)blockIdx.x * 3 * SQ + t;
  *(float4*)(part + base)        = make_float4(m[0],m[1],m[2],m[3]);
  *(float4*)(part + base + SQ)   = make_float4(s1[0],s1[1],s1[2],s1[3]);
  *(float4*)(part + base + 2*SQ) = make_float4(s2[0],s2[1],s2[2],s2[3]);
}

__global__ void col_merge(const float* __restrict__ part, const float* __restrict__ itau,
                          float* __restrict__ Mc, float* __restrict__ S1c, float* __restrict__ S2c){
  int idx = blockIdx.x*256 + threadIdx.x;
  int b = idx >> 10;
  int t = idx & 1023;
  float it = itau[b];
  float M = -1e30f;
  for (int ch = 0; ch < NCH; ++ch)
    M = fmaxf(M, part[(size_t)(b*NCH+ch)*3*SQ + t]);
  float s1 = 0.f, s2 = 0.f;
  for (int ch = 0; ch < NCH; ++ch){
    size_t base = (size_t)(b*NCH+ch)*3*SQ + t;
    float mm = part[base];
    s1 += part[base +   SQ] * expf(mm - M);
    s2 += part[base + 2*SQ] * expf((mm - M)*it);
  }
  Mc[idx] = M; S1c[idx] = s1; S2c[idx] = s2;
}

// ---------------- finalize ----------------
__global__ __launch_bounds__(256)
void finalize(const float* __restrict__ scores,
              const float* __restrict__ add_src, const float* __restrict__ add_tgt,
              const float* __restrict__ itau,
              const float* __restrict__ Mr, const float* __restrict__ S1r, const float* __restrict__ S2r,
              const float* __restrict__ Mc, const float* __restrict__ S1c, const float* __restrict__ S2c,
              float* __restrict__ out0, float* __restrict__ out1){
  int row = blockIdx.x;
  int b = row >> 10;
  float Mrv = Mr[row], s1r = S1r[row], s2r = S2r[row];
  float ads = add_src[row];
  float itt = itau[NB + b], its = itau[b];
  int t = threadIdx.x << 2;
  size_t off = (size_t)row*SQ + t;
  float4 x4  = *(const float4*)(scores + off);
  int bt = b*SQ + t;
  float4 at4 = *(const float4*)(add_tgt + bt);
  float4 mc4 = *(const float4*)(Mc  + bt);
  float4 c14 = *(const float4*)(S1c + bt);
  float4 c24 = *(const float4*)(S2c + bt);
  const float* xp  = (const float*)&x4;
  const float* atp = (const float*)&at4;
  const float* mcp = (const float*)&mc4;
  const float* c1p = (const float*)&c14;
  const float* c2p = (const float*)&c24;
  float o0[4], o1[4];
  #pragma unroll
  for (int j = 0; j < 4; ++j){
    float x  = xp[j];
    float xs = x + atp[j];
    float ps = expf(xs - Mrv) / s1r;
    float qs = expf((xs - Mrv)*itt) / s2r;
    float xt = x + ads;
    float pt = expf(xt - mcp[j]) / c1p[j];
    float qt = expf((xt - mcp[j])*its) / c2p[j];
    o0[j] = (ps > 1e-3f && pt > 1e-3f) ? 1.0f : 0.0f;
    o1[j] = 2.0f*qs*qt / (qs + qt + 1e-9f);
  }
  *(float4*)(out0 + off) = make_float4(o0[0],o0[1],o0[2],o0[3]);
  *(float4*)(out1 + off) = make_float4(o1[0],o1[1],o1[2],o1[3]);
}

extern "C" void kernel_launch(void* const* d_in, const int* in_sizes, int n_in,
                              void* d_out, int out_size, void* d_ws, size_t ws_size,
                              hipStream_t stream){
  const float* hsrc = (const float*)d_in[0];
  const float* htgt = (const float*)d_in[1];
  const int*   isrc = (const int*)d_in[2];
  const int*   itgt = (const int*)d_in[3];

  float* out0 = (float*)d_out;
  float* out1 = out0 + (size_t)NB*SQ*SQ;
  float* W = (float*)d_ws;

  const size_t NSQ2 = (size_t)NB*SQ*SQ;              // 16,777,216
  // fast-path ws layout (floats)
  const size_t need_fast = (NSQ2 + 16384*2 + 32 + 6*NB*SQ + (size_t)NB*NCH*3*SQ) * 4;

  if (ws_size >= need_fast){
    float* scores  = W;                         // 16M floats
    float* add_src = W + NSQ2;
    float* add_tgt = add_src + NB*SQ;
    float* itau    = add_tgt + NB*SQ;
    float* Mr      = itau + 32;
    float* S1r     = Mr  + NB*SQ;
    float* S2r     = S1r + NB*SQ;
    float* Mc      = S2r + NB*SQ;
    float* S1c     = Mc  + NB*SQ;
    float* S2c     = S1c + NB*SQ;
    float* part    = S2c + NB*SQ;

    _Float16* Ahi = (_Float16*)out0;            // planes live in d_out halves until finalize
    _Float16* Alo = Ahi + NSQ2;
    _Float16* Bhi = (_Float16*)out1;
    _Float16* Blo = Bhi + NSQ2;

    prep_kernel<<<NB, 256, 0, stream>>>(isrc, itgt, add_src, add_tgt, itau);
    convert_split<<<NSQ2/1024, 256, 0, stream>>>(hsrc, Ahi, Alo);
    convert_split<<<NSQ2/1024, 256, 0, stream>>>(htgt, Bhi, Blo);
    gemm_split<<<1024, 256, 0, stream>>>(Ahi, Alo, Bhi, Blo, scores);
    row_stats<<<NB*SQ/4, 256, 0, stream>>>(scores, add_tgt, itau, Mr, S1r, S2r);
    col_part<<<NB*NCH, 256, 0, stream>>>(scores, add_src, itau, part);
    col_merge<<<NB*SQ/256, 256, 0, stream>>>(part, itau, Mc, S1c, S2c);
    finalize<<<NB*SQ, 256, 0, stream>>>(scores, add_src, add_tgt, itau,
                                        Mr, S1r, S2r, Mc, S1c, S2c, out0, out1);
  } else {
    // fallback: round-1 fp32 path, scores staged in out1
    float* scores  = out1;
    float* add_src = W;
    float* add_tgt = W + 16384;
    float* itau    = W + 32768;
    float* Mr      = W + 32800;
    float* S1r     = Mr  + NB*SQ;
    float* S2r     = S1r + NB*SQ;
    float* Mc      = S2r + NB*SQ;
    float* S1c     = Mc  + NB*SQ;
    float* S2c     = S1c + NB*SQ;
    float* part    = S2c + NB*SQ;

    prep_kernel<<<NB, 256, 0, stream>>>(isrc, itgt, add_src, add_tgt, itau);
    gemm_nt<<<dim3(8, 8, NB), 256, 0, stream>>>(hsrc, htgt, scores);
    row_stats<<<NB*SQ/4, 256, 0, stream>>>(scores, add_tgt, itau, Mr, S1r, S2r);
    col_part<<<NB*NCH, 256, 0, stream>>>(scores, add_src, itau, part);
    col_merge<<<NB*SQ/256, 256, 0, stream>>>(part, itau, Mc, S1c, S2c);
    finalize<<<NB*SQ, 256, 0, stream>>>(scores, add_src, add_tgt, itau,
                                        Mr, S1r, S2r, Mc, S1c, S2c, out0, out1);
  }
}

// Round 6
// 282.045 us; speedup vs baseline: 1.0281x; 1.0188x over previous
//
#include <hip/hip_runtime.h>
#include <math.h>
#include <stdint.h>

#define NB 16
#define SQ 1024
#define DD 1024

typedef _Float16 f16x8 __attribute__((ext_vector_type(8)));
typedef _Float16 f16x4 __attribute__((ext_vector_type(4)));
typedef float f32x4 __attribute__((ext_vector_type(4)));

// ---------------- prep: special-token masks, lengths, temperatures ----------------
__global__ void prep_kernel(const int* __restrict__ ids_src, const int* __restrict__ ids_tgt,
                            float* __restrict__ add_src, float* __restrict__ add_tgt,
                            float* __restrict__ itau){
  int b = blockIdx.x;
  __shared__ int csrc, ctgt;
  if (threadIdx.x == 0){ csrc = 0; ctgt = 0; }
  __syncthreads();
  int ls = 0, lt = 0;
  for (int i = threadIdx.x; i < SQ; i += blockDim.x){
    int id = ids_src[b*SQ + i];
    bool sp = (id == 0) || (id == 101) || (id == 102);
    add_src[b*SQ + i] = sp ? -10000.0f : 0.0f;
    ls += sp ? 0 : 1;
    id = ids_tgt[b*SQ + i];
    sp = (id == 0) || (id == 101) || (id == 102);
    add_tgt[b*SQ + i] = sp ? -10000.0f : 0.0f;
    lt += sp ? 0 : 1;
  }
  atomicAdd(&csrc, ls);
  atomicAdd(&ctgt, lt);
  __syncthreads();
  if (threadIdx.x == 0){
    itau[b]      = 1.0f / sqrtf((float)csrc);   // 1/sqrt(len_src)
    itau[NB + b] = 1.0f / sqrtf((float)ctgt);   // 1/sqrt(len_tgt)
  }
}

// ---------------- split conversion: fp32 -> hi fp16 + lo fp16 (both inputs, one launch) ----------------
__global__ __launch_bounds__(256)
void convert_split2(const float* __restrict__ X0, const float* __restrict__ X1,
                    _Float16* __restrict__ H0, _Float16* __restrict__ L0,
                    _Float16* __restrict__ H1, _Float16* __restrict__ L1){
  const float* X = blockIdx.y ? X1 : X0;
  _Float16* Hi = blockIdx.y ? H1 : H0;
  _Float16* Lo = blockIdx.y ? L1 : L0;
  size_t i = ((size_t)blockIdx.x*256 + threadIdx.x)*4;
  float4 v = *(const float4*)(X + i);
  float xs[4] = {v.x, v.y, v.z, v.w};
  f16x4 h, l;
  #pragma unroll
  for (int j = 0; j < 4; ++j){
    _Float16 hh = (_Float16)xs[j];
    h[j] = hh;
    l[j] = (_Float16)((xs[j] - (float)hh) * 4096.0f);
  }
  *(f16x4*)(Hi + i) = h;
  *(f16x4*)(Lo + i) = l;
}

// ---------------- split-fp16 MFMA GEMM: scores[b] = hsrc[b] @ htgt[b]^T ----------------
// 128x128 tile, BK=32, 4 waves (2x2 of 64x64), mfma_f32_16x16x32_f16, double-buffered LDS,
// global_load_lds w16. Swizzle swz(row)=(row>>1)&3 applied to BOTH the pre-swizzled global
// source and the ds_read address (rule 21): span-starts cover all 8 positions x2 lanes ->
// free 2-way LDS regime (was 4-way with row&3).
typedef const uint32_t __attribute__((address_space(1))) gu32_t;
typedef uint32_t __attribute__((address_space(3))) su32_t;

__device__ __forceinline__ void gload16(const void* g, void* l){
  __builtin_amdgcn_global_load_lds((gu32_t*)g, (su32_t*)l, 16, 0, 0);
}

#define NKS 32   // 1024/32

__global__ __launch_bounds__(256, 2)
void gemm_split(const _Float16* __restrict__ Ahi, const _Float16* __restrict__ Alo,
                const _Float16* __restrict__ Bhi, const _Float16* __restrict__ Blo,
                float* __restrict__ C){
  __shared__ _Float16 lds[2][4][128*32];   // [buf][plane: Ahi,Alo,Bhi,Blo][row*32 + swizzled k]
  const int tid  = threadIdx.x;
  const int wave = tid >> 6;
  const int lane = tid & 63;

  // XCD-aware swizzle (1024 blocks, 1024 % 8 == 0 -> bijective)
  int bid = blockIdx.x;
  int wg  = (bid & 7) * (1024/8) + (bid >> 3);
  int b   = wg >> 6;
  int by  = (wg >> 3) & 7;
  int bx  = wg & 7;

  const size_t abase = ((size_t)b*SQ + by*128) * DD;
  const size_t bbase = ((size_t)b*SQ + bx*128) * DD;
  const _Float16* srcs[4] = {Ahi + abase, Alo + abase, Bhi + bbase, Blo + bbase};

  // staging geometry: thread i covers LDS 16B slot i (linear); global source pre-swizzled
  const uint32_t rr = tid >> 2;                      // row within 64-row issue
  const uint32_t sl = (tid & 3) ^ ((rr >> 1) & 3);   // swizzled k-slot (8 fp16 each)
  const size_t  goff = (size_t)rr*DD + sl*8;

  // fragment read offsets (fp16 elems): row*32 + swizzled_slot*8
  const int lr  = lane & 15;
  const int ls8 = (((lane >> 4) ^ ((lr >> 1) & 3)) << 3);
  const int wm  = (wave >> 1) * 64;
  const int wn  = (wave & 1) * 64;
  const int aoffL = (wm + lr)*32 + ls8;
  const int boffL = (wn + lr)*32 + ls8;

  f32x4 accm[4][4], accc[4][4];
  #pragma unroll
  for (int m = 0; m < 4; ++m)
    #pragma unroll
    for (int n = 0; n < 4; ++n){ accm[m][n] = (f32x4)0.0f; accc[m][n] = (f32x4)0.0f; }

  // prologue stage into buf 0
  {
    #pragma unroll
    for (int p = 0; p < 4; ++p){
      const _Float16* g = srcs[p] + goff;
      _Float16* l0 = &lds[0][p][0] + wave*512;
      gload16(g, l0);
      gload16(g + 64*DD, l0 + 2048);
    }
  }
  __syncthreads();

  int buf = 0;
  for (int t = 0; t < NKS; ++t){
    if (t + 1 < NKS){
      const int k0 = (t + 1) * 32;
      #pragma unroll
      for (int p = 0; p < 4; ++p){
        const _Float16* g = srcs[p] + k0 + goff;
        _Float16* l0 = &lds[buf^1][p][0] + wave*512;
        gload16(g, l0);
        gload16(g + 64*DD, l0 + 2048);
      }
    }

    f16x8 ah[4], al[4], bh[4], bl[4];
    #pragma unroll
    for (int m = 0; m < 4; ++m){
      ah[m] = *(const f16x8*)&lds[buf][0][aoffL + m*512];
      al[m] = *(const f16x8*)&lds[buf][1][aoffL + m*512];
      bh[m] = *(const f16x8*)&lds[buf][2][boffL + m*512];
      bl[m] = *(const f16x8*)&lds[buf][3][boffL + m*512];
    }
    #pragma unroll
    for (int m = 0; m < 4; ++m)
      #pragma unroll
      for (int n = 0; n < 4; ++n){
        accm[m][n] = __builtin_amdgcn_mfma_f32_16x16x32_f16(ah[m], bh[n], accm[m][n], 0, 0, 0);
        accc[m][n] = __builtin_amdgcn_mfma_f32_16x16x32_f16(ah[m], bl[n], accc[m][n], 0, 0, 0);
        accc[m][n] = __builtin_amdgcn_mfma_f32_16x16x32_f16(al[m], bh[n], accc[m][n], 0, 0, 0);
      }
    __syncthreads();
    buf ^= 1;
  }

  // epilogue: C/D layout col=lane&15, row=(lane>>4)*4+reg
  float* Cb = C + ((size_t)b*SQ + by*128 + wm)*SQ + bx*128 + wn;
  const float inv = 1.0f / 4096.0f;
  const int r0 = (lane >> 4) * 4;
  const int c0 = lane & 15;
  #pragma unroll
  for (int m = 0; m < 4; ++m)
    #pragma unroll
    for (int n = 0; n < 4; ++n){
      #pragma unroll
      for (int j = 0; j < 4; ++j){
        float r = accm[m][n][j] + accc[m][n][j]*inv;
        Cb[(size_t)(m*16 + r0 + j)*SQ + n*16 + c0] = r;
      }
    }
}

// ---------------- fp32 fallback GEMM ----------------
__global__ __launch_bounds__(256)
void gemm_nt(const float* __restrict__ A, const float* __restrict__ Bm, float* __restrict__ C){
  __shared__ float As[32][132];
  __shared__ float Bs[32][132];
  const int b = blockIdx.z;
  const float* Ab = A  + ((size_t)b*SQ + blockIdx.y*128) * DD;
  const float* Bb = Bm + ((size_t)b*SQ + blockIdx.x*128) * DD;
  const int tid = threadIdx.x;
  const int lr = tid >> 3;
  const int lc = (tid & 7) << 2;
  const int tx = tid & 15;
  const int ty = tid >> 4;

  float acc[8][8];
  #pragma unroll
  for (int i = 0; i < 8; ++i)
    #pragma unroll
    for (int j = 0; j < 8; ++j) acc[i][j] = 0.0f;

  for (int k0 = 0; k0 < DD; k0 += 32){
    #pragma unroll
    for (int p = 0; p < 4; ++p){
      int row = p*32 + lr;
      float4 va = *(const float4*)(Ab + (size_t)row*DD + k0 + lc);
      float4 vb = *(const float4*)(Bb + (size_t)row*DD + k0 + lc);
      As[lc+0][row] = va.x; As[lc+1][row] = va.y; As[lc+2][row] = va.z; As[lc+3][row] = va.w;
      Bs[lc+0][row] = vb.x; Bs[lc+1][row] = vb.y; Bs[lc+2][row] = vb.z; Bs[lc+3][row] = vb.w;
    }
    __syncthreads();
    #pragma unroll
    for (int k = 0; k < 32; ++k){
      float a[8], bb[8];
      *(float4*)(a)    = *(const float4*)&As[k][ty*4];
      *(float4*)(a+4)  = *(const float4*)&As[k][64 + ty*4];
      *(float4*)(bb)   = *(const float4*)&Bs[k][tx*4];
      *(float4*)(bb+4) = *(const float4*)&Bs[k][64 + tx*4];
      #pragma unroll
      for (int i = 0; i < 8; ++i)
        #pragma unroll
        for (int j = 0; j < 8; ++j)
          acc[i][j] = fmaf(a[i], bb[j], acc[i][j]);
    }
    __syncthreads();
  }

  float* Cb = C + (size_t)b*SQ*SQ + (size_t)(blockIdx.y*128)*SQ + blockIdx.x*128;
  #pragma unroll
  for (int i = 0; i < 8; ++i){
    int r = (i < 4) ? (ty*4 + i) : (64 + ty*4 + (i-4));
    *(float4*)(Cb + (size_t)r*SQ + tx*4)      = make_float4(acc[i][0],acc[i][1],acc[i][2],acc[i][3]);
    *(float4*)(Cb + (size_t)r*SQ + 64 + tx*4) = make_float4(acc[i][4],acc[i][5],acc[i][6],acc[i][7]);
  }
}

// ---------------- fused stats: exact row stats + column partials, one scores read ----------------
// One block per (b, 16-row chunk). 256 threads x float4 cols = full 1024-col coverage,
// so row stats are exact within the block. 16x float4 scores buffered in registers;
// col partials use two-pass max-then-sum (no online-rescale expf).
#define NCH 64
__global__ __launch_bounds__(256)
void stats_pass(const float* __restrict__ scores,
                const float* __restrict__ add_src, const float* __restrict__ add_tgt,
                const float* __restrict__ itau,
                float* __restrict__ Mr, float* __restrict__ S1r, float* __restrict__ S2r,
                float* __restrict__ part){
  __shared__ float redm[16][4];
  __shared__ float red1[16][4];
  __shared__ float red2[16][4];
  const int b  = blockIdx.x >> 6;
  const int ch = blockIdx.x & 63;
  const int tid = threadIdx.x;
  const int wv = tid >> 6;
  const int t0 = tid << 2;
  const float its = itau[b];        // col temperature 1/sqrt(len_src)
  const float itt = itau[NB + b];   // row temperature 1/sqrt(len_tgt)

  const float* p = scores + ((size_t)b*SQ + ch*16)*SQ + t0;
  float4 at4 = *(const float4*)(add_tgt + b*SQ + t0);

  float4 x[16];
  #pragma unroll
  for (int s = 0; s < 16; ++s) x[s] = *(const float4*)(p + (size_t)s*SQ);

  // ---- row path: max over full row (block-wide), then exp sums ----
  #pragma unroll
  for (int s = 0; s < 16; ++s){
    float m = fmaxf(fmaxf(x[s].x + at4.x, x[s].y + at4.y),
                    fmaxf(x[s].z + at4.z, x[s].w + at4.w));
    #pragma unroll
    for (int o = 32; o > 0; o >>= 1) m = fmaxf(m, __shfl_xor(m, o));
    if ((tid & 63) == 0) redm[s][wv] = m;
  }
  __syncthreads();
  float Mrow[16];
  #pragma unroll
  for (int s = 0; s < 16; ++s)
    Mrow[s] = fmaxf(fmaxf(redm[s][0], redm[s][1]), fmaxf(redm[s][2], redm[s][3]));

  #pragma unroll
  for (int s = 0; s < 16; ++s){
    float d0 = x[s].x + at4.x - Mrow[s];
    float d1 = x[s].y + at4.y - Mrow[s];
    float d2 = x[s].z + at4.z - Mrow[s];
    float d3 = x[s].w + at4.w - Mrow[s];
    float s1 = expf(d0) + expf(d1) + expf(d2) + expf(d3);
    float s2 = expf(d0*itt) + expf(d1*itt) + expf(d2*itt) + expf(d3*itt);
    #pragma unroll
    for (int o = 32; o > 0; o >>= 1){ s1 += __shfl_xor(s1, o); s2 += __shfl_xor(s2, o); }
    if ((tid & 63) == 0){ red1[s][wv] = s1; red2[s][wv] = s2; }
  }
  __syncthreads();
  if (tid < 16){
    int s = tid;
    int row = b*SQ + ch*16 + s;
    Mr[row]  = fmaxf(fmaxf(redm[s][0], redm[s][1]), fmaxf(redm[s][2], redm[s][3]));
    S1r[row] = red1[s][0] + red1[s][1] + red1[s][2] + red1[s][3];
    S2r[row] = red2[s][0] + red2[s][1] + red2[s][2] + red2[s][3];
  }

  // ---- col path: partial (16 rows) max-then-sum per column ----
  float asv[16];
  #pragma unroll
  for (int s = 0; s < 16; ++s) asv[s] = add_src[b*SQ + ch*16 + s];

  float cm0 = -1e30f, cm1 = -1e30f, cm2 = -1e30f, cm3 = -1e30f;
  #pragma unroll
  for (int s = 0; s < 16; ++s){
    cm0 = fmaxf(cm0, x[s].x + asv[s]);
    cm1 = fmaxf(cm1, x[s].y + asv[s]);
    cm2 = fmaxf(cm2, x[s].z + asv[s]);
    cm3 = fmaxf(cm3, x[s].w + asv[s]);
  }
  float c10 = 0.f, c11 = 0.f, c12 = 0.f, c13 = 0.f;
  float c20 = 0.f, c21 = 0.f, c22 = 0.f, c23 = 0.f;
  #pragma unroll
  for (int s = 0; s < 16; ++s){
    float d0 = x[s].x + asv[s] - cm0;
    float d1 = x[s].y + asv[s] - cm1;
    float d2 = x[s].z + asv[s] - cm2;
    float d3 = x[s].w + asv[s] - cm3;
    c10 += expf(d0); c11 += expf(d1); c12 += expf(d2); c13 += expf(d3);
    c20 += expf(d0*its); c21 += expf(d1*its); c22 += expf(d2*its); c23 += expf(d3*its);
  }
  size_t base = (size_t)blockIdx.x * 3 * SQ + t0;   // [b*NCH+ch][3][S]
  *(float4*)(part + base)        = make_float4(cm0, cm1, cm2, cm3);
  *(float4*)(part + base + SQ)   = make_float4(c10, c11, c12, c13);
  *(float4*)(part + base + 2*SQ) = make_float4(c20, c21, c22, c23);
}

__global__ void col_merge(const float* __restrict__ part, const float* __restrict__ itau,
                          float* __restrict__ Mc, float* __restrict__ S1c, float* __restrict__ S2c){
  int idx = blockIdx.x*256 + threadIdx.x;
  int b = idx >> 10;
  int t = idx & 1023;
  float it = itau[b];
  float M = -1e30f;
  for (int ch = 0; ch < NCH; ++ch)
    M = fmaxf(M, part[(size_t)(b*NCH+ch)*3*SQ + t]);
  float s1 = 0.f, s2 = 0.f;
  for (int ch = 0; ch < NCH; ++ch){
    size_t base = (size_t)(b*NCH+ch)*3*SQ + t;
    float mm = part[base];
    s1 += part[base +   SQ] * expf(mm - M);
    s2 += part[base + 2*SQ] * expf((mm - M)*it);
  }
  Mc[idx] = M; S1c[idx] = s1; S2c[idx] = s2;
}

// ---------------- finalize ----------------
__global__ __launch_bounds__(256)
void finalize(const float* __restrict__ scores,
              const float* __restrict__ add_src, const float* __restrict__ add_tgt,
              const float* __restrict__ itau,
              const float* __restrict__ Mr, const float* __restrict__ S1r, const float* __restrict__ S2r,
              const float* __restrict__ Mc, const float* __restrict__ S1c, const float* __restrict__ S2c,
              float* __restrict__ out0, float* __restrict__ out1){
  int row = blockIdx.x;
  int b = row >> 10;
  float Mrv = Mr[row], s1r = S1r[row], s2r = S2r[row];
  float ads = add_src[row];
  float itt = itau[NB + b], its = itau[b];
  int t = threadIdx.x << 2;
  size_t off = (size_t)row*SQ + t;
  float4 x4  = *(const float4*)(scores + off);
  int bt = b*SQ + t;
  float4 at4 = *(const float4*)(add_tgt + bt);
  float4 mc4 = *(const float4*)(Mc  + bt);
  float4 c14 = *(const float4*)(S1c + bt);
  float4 c24 = *(const float4*)(S2c + bt);
  const float* xp  = (const float*)&x4;
  const float* atp = (const float*)&at4;
  const float* mcp = (const float*)&mc4;
  const float* c1p = (const float*)&c14;
  const float* c2p = (const float*)&c24;
  float o0[4], o1[4];
  #pragma unroll
  for (int j = 0; j < 4; ++j){
    float x  = xp[j];
    float xs = x + atp[j];
    float ps = expf(xs - Mrv) / s1r;
    float qs = expf((xs - Mrv)*itt) / s2r;
    float xt = x + ads;
    float pt = expf(xt - mcp[j]) / c1p[j];
    float qt = expf((xt - mcp[j])*its) / c2p[j];
    o0[j] = (ps > 1e-3f && pt > 1e-3f) ? 1.0f : 0.0f;
    o1[j] = 2.0f*qs*qt / (qs + qt + 1e-9f);
  }
  *(float4*)(out0 + off) = make_float4(o0[0],o0[1],o0[2],o0[3]);
  *(float4*)(out1 + off) = make_float4(o1[0],o1[1],o1[2],o1[3]);
}

extern "C" void kernel_launch(void* const* d_in, const int* in_sizes, int n_in,
                              void* d_out, int out_size, void* d_ws, size_t ws_size,
                              hipStream_t stream){
  const float* hsrc = (const float*)d_in[0];
  const float* htgt = (const float*)d_in[1];
  const int*   isrc = (const int*)d_in[2];
  const int*   itgt = (const int*)d_in[3];

  float* out0 = (float*)d_out;
  float* out1 = out0 + (size_t)NB*SQ*SQ;
  float* W = (float*)d_ws;

  const size_t NSQ2 = (size_t)NB*SQ*SQ;              // 16,777,216
  const size_t need_fast = (NSQ2 + 16384*2 + 32 + 6*NB*SQ + (size_t)NB*NCH*3*SQ) * 4;

  if (ws_size >= need_fast){
    float* scores  = W;                         // 16M floats
    float* add_src = W + NSQ2;
    float* add_tgt = add_src + NB*SQ;
    float* itau    = add_tgt + NB*SQ;
    float* Mr      = itau + 32;
    float* S1r     = Mr  + NB*SQ;
    float* S2r     = S1r + NB*SQ;
    float* Mc      = S2r + NB*SQ;
    float* S1c     = Mc  + NB*SQ;
    float* S2c     = S1c + NB*SQ;
    float* part    = S2c + NB*SQ;

    _Float16* Ahi = (_Float16*)out0;            // planes live in d_out halves until finalize
    _Float16* Alo = Ahi + NSQ2;
    _Float16* Bhi = (_Float16*)out1;
    _Float16* Blo = Bhi + NSQ2;

    prep_kernel<<<NB, 256, 0, stream>>>(isrc, itgt, add_src, add_tgt, itau);
    convert_split2<<<dim3(NSQ2/1024, 2), 256, 0, stream>>>(hsrc, htgt, Ahi, Alo, Bhi, Blo);
    gemm_split<<<1024, 256, 0, stream>>>(Ahi, Alo, Bhi, Blo, scores);
    stats_pass<<<NB*NCH, 256, 0, stream>>>(scores, add_src, add_tgt, itau, Mr, S1r, S2r, part);
    col_merge<<<NB*SQ/256, 256, 0, stream>>>(part, itau, Mc, S1c, S2c);
    finalize<<<NB*SQ, 256, 0, stream>>>(scores, add_src, add_tgt, itau,
                                        Mr, S1r, S2r, Mc, S1c, S2c, out0, out1);
  } else {
    // fallback: fp32 GEMM path, scores staged in out1 (finalize overwrites in place)
    float* scores  = out1;
    float* add_src = W;
    float* add_tgt = W + 16384;
    float* itau    = W + 32768;
    float* Mr      = W + 32800;
    float* S1r     = Mr  + NB*SQ;
    float* S2r     = S1r + NB*SQ;
    float* Mc      = S2r + NB*SQ;
    float* S1c     = Mc  + NB*SQ;
    float* S2c     = S1c + NB*SQ;
    float* part    = S2c + NB*SQ;

    prep_kernel<<<NB, 256, 0, stream>>>(isrc, itgt, add_src, add_tgt, itau);
    gemm_nt<<<dim3(8, 8, NB), 256, 0, stream>>>(hsrc, htgt, scores);
    stats_pass<<<NB*NCH, 256, 0, stream>>>(scores, add_src, add_tgt, itau, Mr, S1r, S2r, part);
    col_merge<<<NB*SQ/256, 256, 0, stream>>>(part, itau, Mc, S1c, S2c);
    finalize<<<NB*SQ, 256, 0, stream>>>(scores, add_src, add_tgt, itau,
                                        Mr, S1r, S2r, Mc, S1c, S2c, out0, out1);
  }
}